// Round 2
// baseline (1047.193 us; speedup 1.0000x reference)
//
#include <hip/hip_runtime.h>
#include <hip/hip_bf16.h>

#define NN 50000
#define NE 800000
#define IND 128
#define C 64   // FEAT = HID = OUT

typedef __hip_bfloat16 bf16;

__device__ __forceinline__ float to_f(float v) { return v; }
__device__ __forceinline__ float to_f(bf16 v)  { return __bfloat162float(v); }

// --- dtype detect: are float inputs fp32 (flag=1) or bf16 (flag=0)? --------
// Looks at the low-16-bit "exponent" field of the first 64 words of x.
// bf16 data: low half is a bf16 value of N(0,1) -> exponent in [90,144].
// fp32 data: low half is mantissa bits -> ~uniform, rarely in range.
__global__ void detect_kernel(const unsigned* __restrict__ xu, int* __restrict__ flag) {
    int lane = threadIdx.x;
    unsigned u  = xu[lane];
    unsigned ex = (u >> 7) & 0xFF;
    int vote = (ex >= 90 && ex <= 144) ? 1 : 0;
#pragma unroll
    for (int off = 32; off; off >>= 1) vote += __shfl_xor(vote, off, 64);
    if (lane == 0) *flag = (vote < 40) ? 1 : 0;
}

// --- degree count ----------------------------------------------------------
__global__ void count_kernel(const int* __restrict__ tgt, float* __restrict__ cnt) {
    int e = blockIdx.x * blockDim.x + threadIdx.x;
    if (e < NE) atomicAdd(&cnt[tgt[e]], 1.0f);
}

__global__ void inv_kernel(float* __restrict__ cnt) {
    int n = blockIdx.x * blockDim.x + threadIdx.x;
    if (n < NN) cnt[n] = 1.0f / fmaxf(cnt[n], 1.0f);
}

// --- linear_pre ------------------------------------------------------------
template <typename T>
__device__ __forceinline__ void pre_impl(const T* __restrict__ x, const T* __restrict__ w,
                                         const T* __restrict__ b, float* __restrict__ h) {
    __shared__ float xs[4][IND];
    int g  = threadIdx.x >> 6;
    int fo = threadIdx.x & 63;
    int n  = blockIdx.x * 4 + g;           // grid is exact: n < NN always
    xs[g][fo]      = to_f(x[n * IND + fo]);
    xs[g][fo + 64] = to_f(x[n * IND + fo + 64]);
    __syncthreads();
    float acc = to_f(b[fo]);
#pragma unroll 8
    for (int fi = 0; fi < IND; ++fi)
        acc += xs[g][fi] * to_f(w[fi * C + fo]);
    h[n * C + fo] = acc;
}

__global__ void pre_kernel(const void* x, const void* w, const void* b,
                           const int* __restrict__ flagp, float* __restrict__ h) {
    if (*flagp) pre_impl<float>((const float*)x, (const float*)w, (const float*)b, h);
    else        pre_impl<bf16>((const bf16*)x, (const bf16*)w, (const bf16*)b, h);
}

// --- g[n, c*64+fo] = sum_fi h[n,fi] * W[c*64+fi, fo] -----------------------
template <typename T>
__device__ __forceinline__ void g_impl(const float* __restrict__ h, const T* __restrict__ w,
                                       float* __restrict__ g) {
    __shared__ float hs[4][C];
    int gl = threadIdx.x >> 6;
    int fo = threadIdx.x & 63;
    int n  = blockIdx.x * 4 + gl;          // grid exact
    hs[gl][fo] = h[n * C + fo];
    __syncthreads();
    float a0 = 0.f, a1 = 0.f, a2 = 0.f;
#pragma unroll 8
    for (int fi = 0; fi < C; ++fi) {
        float hv = hs[gl][fi];
        a0 += hv * to_f(w[fi * C + fo]);
        a1 += hv * to_f(w[(64 + fi) * C + fo]);
        a2 += hv * to_f(w[(128 + fi) * C + fo]);
    }
    float* go = g + n * 192;
    go[fo] = a0; go[64 + fo] = a1; go[128 + fo] = a2;
}

__global__ void g_kernel(const float* __restrict__ h, const void* w,
                         const int* __restrict__ flagp, float* __restrict__ g) {
    if (*flagp) g_impl<float>(h, (const float*)w, g);
    else        g_impl<bf16>(h, (const bf16*)w, g);
}

// --- edge scatter: acc[tgt,f] += sum_c ea[e,c]*g[src, c*64+f] --------------
template <typename T>
__device__ __forceinline__ void scatter_impl(const float* __restrict__ g, const int* __restrict__ src,
                                             const int* __restrict__ tgt, const T* __restrict__ ea,
                                             float* __restrict__ acc) {
    int t = blockIdx.x * blockDim.x + threadIdx.x;
    int e = t >> 6;
    int f = t & 63;
    if (e >= NE) return;
    int j = src[e], i = tgt[e];
    float e0 = to_f(ea[e * 3 + 0]);
    float e1 = to_f(ea[e * 3 + 1]);
    float e2 = to_f(ea[e * 3 + 2]);
    const float* gj = g + j * 192;
    float v = e0 * gj[f] + e1 * gj[64 + f] + e2 * gj[128 + f];
    atomicAdd(&acc[i * C + f], v);
}

__global__ void scatter_kernel(const float* __restrict__ g, const int* __restrict__ src,
                               const int* __restrict__ tgt, const void* ea,
                               const int* __restrict__ flagp, float* __restrict__ acc) {
    if (*flagp) scatter_impl<float>(g, src, tgt, (const float*)ea, acc);
    else        scatter_impl<bf16>(g, src, tgt, (const bf16*)ea, acc);
}

// --- finalize layers 1,2: h = relu(acc*inv + b) (in place: acc aliases h) --
template <typename T>
__device__ __forceinline__ void fin_impl(const float* __restrict__ acc, const float* __restrict__ inv,
                                         const T* __restrict__ b, float* __restrict__ h) {
    int t = blockIdx.x * blockDim.x + threadIdx.x;   // grid exact: t < NN*C
    int n = t >> 6, f = t & 63;
    float v = acc[t] * inv[n] + to_f(b[f]);
    h[t] = fmaxf(v, 0.0f);
}

__global__ void finalize_relu(const float* __restrict__ acc, const float* __restrict__ inv,
                              const void* b, const int* __restrict__ flagp,
                              float* __restrict__ h) {
    if (*flagp) fin_impl<float>(acc, inv, (const float*)b, h);
    else        fin_impl<bf16>(acc, inv, (const bf16*)b, h);
}

// --- layer 3 finalize + L2 normalize; output dtype follows flag ------------
template <typename T>
__device__ __forceinline__ void norm_impl(const float* __restrict__ acc, const float* __restrict__ inv,
                                          const T* __restrict__ b, T* __restrict__ out) {
    int n = blockIdx.x;
    int f = threadIdx.x;
    float v = acc[n * C + f] * inv[n] + to_f(b[f]);
    float s = v * v;
#pragma unroll
    for (int off = 32; off; off >>= 1) s += __shfl_xor(s, off, 64);
    float r = v / fmaxf(sqrtf(s), 1e-12f);
    if constexpr (sizeof(T) == 2) out[n * C + f] = __float2bfloat16(r);
    else                          out[n * C + f] = r;
}

__global__ void final_norm(const float* __restrict__ acc, const float* __restrict__ inv,
                           const void* b, const int* __restrict__ flagp, void* out) {
    if (*flagp) norm_impl<float>(acc, inv, (const float*)b, (float*)out);
    else        norm_impl<bf16>(acc, inv, (const bf16*)b, (bf16*)out);
}

extern "C" void kernel_launch(void* const* d_in, const int* in_sizes, int n_in,
                              void* d_out, int out_size, void* d_ws, size_t ws_size,
                              hipStream_t stream) {
    const void* x     = d_in[0];
    const int*  ei    = (const int*)d_in[1];
    const void* ea    = d_in[2];
    const void* pre_w = d_in[3];
    const void* pre_b = d_in[4];
    const void* W[3]  = {d_in[5], d_in[7], d_in[9]};
    const void* B[3]  = {d_in[6], d_in[8], d_in[10]};
    const int* src = ei;
    const int* tgt = ei + NE;

    // ws layout (floats): H/ACC[NN*64] | G[NN*192] | INV[NN] | FLAG
    // H is dead after g_kernel and rewritten by finalize -> alias ACC onto H.
    float* H    = (float*)d_ws;
    float* ACC  = H;
    float* G    = H + NN * C;            //  3,200,000
    float* INV  = G + NN * 192;          // 12,800,000
    int*   FLAG = (int*)(INV + NN);      // 12,850,000  (~51.4 MB total)

    detect_kernel<<<1, 64, 0, stream>>>((const unsigned*)x, FLAG);
    hipMemsetAsync(INV, 0, NN * sizeof(float), stream);
    count_kernel<<<(NE + 255) / 256, 256, 0, stream>>>(tgt, INV);
    inv_kernel<<<(NN + 255) / 256, 256, 0, stream>>>(INV);
    pre_kernel<<<NN / 4, 256, 0, stream>>>(x, pre_w, pre_b, FLAG, H);

    for (int l = 0; l < 3; ++l) {
        g_kernel<<<NN / 4, 256, 0, stream>>>(H, W[l], FLAG, G);
        hipMemsetAsync(ACC, 0, (size_t)NN * C * sizeof(float), stream);
        scatter_kernel<<<(int)(((size_t)NE * 64 + 255) / 256), 256, 0, stream>>>(G, src, tgt, ea, FLAG, ACC);
        if (l < 2)
            finalize_relu<<<NN * C / 256, 256, 0, stream>>>(ACC, INV, B[l], FLAG, H);
        else
            final_norm<<<NN, 64, 0, stream>>>(ACC, INV, B[l], FLAG, d_out);
    }
}

// Round 3
// 948.426 us; speedup vs baseline: 1.1041x; 1.1041x over previous
//
#include <hip/hip_runtime.h>
#include <hip/hip_bf16.h>

#define NN 50000
#define NE 800000
#define IND 128
#define C 64   // FEAT = HID = OUT

typedef __hip_bfloat16 bf16;

__device__ __forceinline__ float to_f(float v) { return v; }
__device__ __forceinline__ float to_f(bf16 v)  { return __bfloat162float(v); }

// --- dtype detect: float inputs fp32 (flag=1) or bf16 (flag=0)? ------------
__global__ void detect_kernel(const unsigned* __restrict__ xu, int* __restrict__ flag) {
    int lane = threadIdx.x;
    unsigned u  = xu[lane];
    unsigned ex = (u >> 7) & 0xFF;
    int vote = (ex >= 90 && ex <= 144) ? 1 : 0;
#pragma unroll
    for (int off = 32; off; off >>= 1) vote += __shfl_xor(vote, off, 64);
    if (lane == 0) *flag = (vote < 40) ? 1 : 0;
}

// --- degree histogram ------------------------------------------------------
__global__ void count_kernel(const int* __restrict__ tgt, int* __restrict__ cnt) {
    int e = blockIdx.x * blockDim.x + threadIdx.x;
    if (e < NE) atomicAdd(&cnt[tgt[e]], 1);
}

// --- single-block exclusive scan over cnt -> off; also inv = 1/max(cnt,1) --
__global__ __launch_bounds__(1024) void scan_kernel(const int* __restrict__ cnt,
                                                    int* __restrict__ off,
                                                    float* __restrict__ inv) {
    __shared__ int wsum[16];
    __shared__ int carry;
    int tid = threadIdx.x, lane = tid & 63, wv = tid >> 6;
    if (tid == 0) carry = 0;
    __syncthreads();
    for (int base = 0; base < NN; base += 1024) {
        int i = base + tid;
        int v = (i < NN) ? cnt[i] : 0;
        int incl = v;
#pragma unroll
        for (int d = 1; d < 64; d <<= 1) { int t = __shfl_up(incl, d, 64); if (lane >= d) incl += t; }
        if (lane == 63) wsum[wv] = incl;
        __syncthreads();
        if (wv == 0) {
            int ws = (lane < 16) ? wsum[lane] : 0;
#pragma unroll
            for (int d = 1; d < 16; d <<= 1) { int t = __shfl_up(ws, d, 64); if (lane >= d) ws += t; }
            if (lane < 16) wsum[lane] = ws;
        }
        __syncthreads();
        int wbase = (wv == 0) ? 0 : wsum[wv - 1];
        int excl = carry + wbase + incl - v;
        if (i < NN) { off[i] = excl; inv[i] = 1.0f / fmaxf((float)v, 1.0f); }
        __syncthreads();
        if (tid == 1023) carry += wsum[15];
        __syncthreads();
    }
    if (tid == 0) off[NN] = NE;
}

// --- place edges sorted by target: record = {e0,e1,e2, src} ---------------
template <typename T>
__device__ __forceinline__ void fill_impl(const int* __restrict__ src, const int* __restrict__ tgt,
                                          const T* __restrict__ ea, const int* __restrict__ off,
                                          int* __restrict__ fill, float4* __restrict__ edge) {
    int e = blockIdx.x * blockDim.x + threadIdx.x;
    if (e >= NE) return;
    int t = tgt[e];
    int p = off[t] + atomicAdd(&fill[t], 1);
    float4 r;
    r.x = to_f(ea[e * 3 + 0]);
    r.y = to_f(ea[e * 3 + 1]);
    r.z = to_f(ea[e * 3 + 2]);
    r.w = __int_as_float(src[e]);
    edge[p] = r;
}

__global__ void fill_kernel(const int* __restrict__ src, const int* __restrict__ tgt,
                            const void* ea, const int* __restrict__ off,
                            const int* __restrict__ flagp,
                            int* __restrict__ fill, float4* __restrict__ edge) {
    if (*flagp) fill_impl<float>(src, tgt, (const float*)ea, off, fill, edge);
    else        fill_impl<bf16>(src, tgt, (const bf16*)ea, off, fill, edge);
}

// --- linear_pre ------------------------------------------------------------
template <typename T>
__device__ __forceinline__ void pre_impl(const T* __restrict__ x, const T* __restrict__ w,
                                         const T* __restrict__ b, float* __restrict__ h) {
    __shared__ float xs[4][IND];
    int g  = threadIdx.x >> 6;
    int fo = threadIdx.x & 63;
    int n  = blockIdx.x * 4 + g;
    xs[g][fo]      = to_f(x[n * IND + fo]);
    xs[g][fo + 64] = to_f(x[n * IND + fo + 64]);
    __syncthreads();
    float acc = to_f(b[fo]);
#pragma unroll 8
    for (int fi = 0; fi < IND; ++fi)
        acc += xs[g][fi] * to_f(w[fi * C + fo]);
    h[n * C + fo] = acc;
}

__global__ __launch_bounds__(256) void pre_kernel(const void* x, const void* w, const void* b,
                                                  const int* __restrict__ flagp, float* __restrict__ h) {
    if (*flagp) pre_impl<float>((const float*)x, (const float*)w, (const float*)b, h);
    else        pre_impl<bf16>((const bf16*)x, (const bf16*)w, (const bf16*)b, h);
}

// --- aggregation: one wave per node, no atomics ----------------------------
// s[n, c*64+f] = inv[n] * sum_{edges e->n} ea_c[e] * h[src[e], f]
__global__ __launch_bounds__(256) void agg_kernel(const float* __restrict__ h,
                                                  const float4* __restrict__ edge,
                                                  const int* __restrict__ off,
                                                  const float* __restrict__ inv,
                                                  float* __restrict__ s) {
    int f = threadIdx.x & 63;
    int n = blockIdx.x * 4 + (threadIdx.x >> 6);
    int beg = off[n], end = off[n + 1];
    float a0 = 0.f, a1 = 0.f, a2 = 0.f;
    int e = beg;
    for (; e + 2 <= end; e += 2) {
        float4 r0 = edge[e];
        float4 r1 = edge[e + 1];
        float h0 = h[(__float_as_int(r0.w) << 6) + f];
        float h1 = h[(__float_as_int(r1.w) << 6) + f];
        a0 += r0.x * h0; a1 += r0.y * h0; a2 += r0.z * h0;
        a0 += r1.x * h1; a1 += r1.y * h1; a2 += r1.z * h1;
    }
    if (e < end) {
        float4 r = edge[e];
        float hv = h[(__float_as_int(r.w) << 6) + f];
        a0 += r.x * hv; a1 += r.y * hv; a2 += r.z * hv;
    }
    float iv = inv[n];
    float* so = s + n * 192;
    so[f] = a0 * iv; so[64 + f] = a1 * iv; so[128 + f] = a2 * iv;
}

// --- dense: out = S @ W + b, fused relu (MODE 0 -> H) or L2-norm (MODE 1) --
template <typename T, int MODE>
__device__ __forceinline__ void gemm_impl(const float* __restrict__ s, const T* __restrict__ w,
                                          const T* __restrict__ b, float* __restrict__ hout,
                                          T* __restrict__ out) {
    __shared__ float Wl[192 * 64];
    __shared__ float srow[4][192];
    int tid = threadIdx.x, fo = tid & 63, wv = tid >> 6;
    for (int i = tid; i < 192 * 64; i += 256) Wl[i] = to_f(w[i]);
    int n = blockIdx.x * 4 + wv;
    const float* sr = s + n * 192;
    srow[wv][fo] = sr[fo]; srow[wv][64 + fo] = sr[64 + fo]; srow[wv][128 + fo] = sr[128 + fo];
    __syncthreads();
    float acc = to_f(b[fo]);
#pragma unroll 8
    for (int k = 0; k < 192; ++k)
        acc += srow[wv][k] * Wl[k * 64 + fo];
    if constexpr (MODE == 0) {
        hout[n * C + fo] = fmaxf(acc, 0.0f);
    } else {
        float sq = acc * acc;
#pragma unroll
        for (int o = 32; o; o >>= 1) sq += __shfl_xor(sq, o, 64);
        float r = acc / fmaxf(sqrtf(sq), 1e-12f);
        if constexpr (sizeof(T) == 2) out[n * C + fo] = __float2bfloat16(r);
        else                          out[n * C + fo] = r;
    }
}

__global__ __launch_bounds__(256) void gemm_relu(const float* __restrict__ s, const void* w,
                                                 const void* b, const int* __restrict__ flagp,
                                                 float* __restrict__ hout) {
    if (*flagp) gemm_impl<float, 0>(s, (const float*)w, (const float*)b, hout, nullptr);
    else        gemm_impl<bf16, 0>(s, (const bf16*)w, (const bf16*)b, hout, nullptr);
}

__global__ __launch_bounds__(256) void gemm_norm(const float* __restrict__ s, const void* w,
                                                 const void* b, const int* __restrict__ flagp,
                                                 void* out) {
    if (*flagp) gemm_impl<float, 1>(s, (const float*)w, (const float*)b, nullptr, (float*)out);
    else        gemm_impl<bf16, 1>(s, (const bf16*)w, (const bf16*)b, nullptr, (bf16*)out);
}

extern "C" void kernel_launch(void* const* d_in, const int* in_sizes, int n_in,
                              void* d_out, int out_size, void* d_ws, size_t ws_size,
                              hipStream_t stream) {
    const void* x     = d_in[0];
    const int*  ei    = (const int*)d_in[1];
    const void* ea    = d_in[2];
    const void* pre_w = d_in[3];
    const void* pre_b = d_in[4];
    const void* W[3]  = {d_in[5], d_in[7], d_in[9]};
    const void* B[3]  = {d_in[6], d_in[8], d_in[10]};
    const int* src = ei;
    const int* tgt = ei + NE;

    // ws layout: EDGE f4[NE] | H[NN*64] | S[NN*192] | OFF[NN+1] | CNT[NN] | FILL[NN] | INV[NN] | FLAG
    float4* EDGE = (float4*)d_ws;                 // 12.8 MB (16B aligned)
    float*  H    = (float*)(EDGE + NE);           // 12.8 MB
    float*  S    = H + (size_t)NN * C;            // 38.4 MB
    int*    OFF  = (int*)(S + (size_t)NN * 192);
    int*    CNT  = OFF + NN + 1;
    int*    FILL = CNT + NN;
    float*  INV  = (float*)(FILL + NN);
    int*    FLAG = (int*)(INV + NN);              // total ~64.6 MB

    detect_kernel<<<1, 64, 0, stream>>>((const unsigned*)x, FLAG);
    hipMemsetAsync(CNT, 0, 2 * NN * sizeof(int), stream);   // zeros CNT and FILL
    count_kernel<<<(NE + 255) / 256, 256, 0, stream>>>(tgt, CNT);
    scan_kernel<<<1, 1024, 0, stream>>>(CNT, OFF, INV);
    fill_kernel<<<(NE + 255) / 256, 256, 0, stream>>>(src, tgt, ea, OFF, FLAG, FILL, EDGE);
    pre_kernel<<<NN / 4, 256, 0, stream>>>(x, pre_w, pre_b, FLAG, H);

    for (int l = 0; l < 3; ++l) {
        agg_kernel<<<NN / 4, 256, 0, stream>>>(H, EDGE, OFF, INV, S);
        if (l < 2)
            gemm_relu<<<NN / 4, 256, 0, stream>>>(S, W[l], B[l], FLAG, H);
        else
            gemm_norm<<<NN / 4, 256, 0, stream>>>(S, W[l], B[l], FLAG, d_out);
    }
}

// Round 4
// 702.094 us; speedup vs baseline: 1.4915x; 1.3509x over previous
//
#include <hip/hip_runtime.h>
#include <hip/hip_bf16.h>

#define NN 50000
#define NE 800000
#define IND 128
#define C 64     // FEAT = HID = OUT
#define NPB 16   // nodes per block in pre/gemm (50000 = 16 * 3125)

typedef __hip_bfloat16 bf16;

__device__ __forceinline__ float to_f(float v) { return v; }
__device__ __forceinline__ float to_f(bf16 v)  { return __bfloat162float(v); }

// --- dtype detect: float inputs fp32 (flag=1) or bf16 (flag=0)? ------------
__global__ void detect_kernel(const unsigned* __restrict__ xu, int* __restrict__ flag) {
    int lane = threadIdx.x;
    unsigned u  = xu[lane];
    unsigned ex = (u >> 7) & 0xFF;
    int vote = (ex >= 90 && ex <= 144) ? 1 : 0;
#pragma unroll
    for (int off = 32; off; off >>= 1) vote += __shfl_xor(vote, off, 64);
    if (lane == 0) *flag = (vote < 40) ? 1 : 0;
}

// --- degree histogram ------------------------------------------------------
__global__ void count_kernel(const int* __restrict__ tgt, int* __restrict__ cnt) {
    int e = blockIdx.x * blockDim.x + threadIdx.x;
    if (e < NE) atomicAdd(&cnt[tgt[e]], 1);
}

// --- single-block exclusive scan over cnt -> off; also inv = 1/max(cnt,1) --
__global__ __launch_bounds__(1024) void scan_kernel(const int* __restrict__ cnt,
                                                    int* __restrict__ off,
                                                    float* __restrict__ inv) {
    __shared__ int wsum[16];
    __shared__ int carry;
    int tid = threadIdx.x, lane = tid & 63, wv = tid >> 6;
    if (tid == 0) carry = 0;
    __syncthreads();
    for (int base = 0; base < NN; base += 1024) {
        int i = base + tid;
        int v = (i < NN) ? cnt[i] : 0;
        int incl = v;
#pragma unroll
        for (int d = 1; d < 64; d <<= 1) { int t = __shfl_up(incl, d, 64); if (lane >= d) incl += t; }
        if (lane == 63) wsum[wv] = incl;
        __syncthreads();
        if (wv == 0) {
            int ws = (lane < 16) ? wsum[lane] : 0;
#pragma unroll
            for (int d = 1; d < 16; d <<= 1) { int t = __shfl_up(ws, d, 64); if (lane >= d) ws += t; }
            if (lane < 16) wsum[lane] = ws;
        }
        __syncthreads();
        int wbase = (wv == 0) ? 0 : wsum[wv - 1];
        int excl = carry + wbase + incl - v;
        if (i < NN) { off[i] = excl; inv[i] = 1.0f / fmaxf((float)v, 1.0f); }
        __syncthreads();
        if (tid == 1023) carry += wsum[15];
        __syncthreads();
    }
    if (tid == 0) off[NN] = NE;
}

// --- place edges sorted by target: record = {e0,e1,e2, src} ----------------
template <typename T>
__device__ __forceinline__ void fill_impl(const int* __restrict__ src, const int* __restrict__ tgt,
                                          const T* __restrict__ ea, const int* __restrict__ off,
                                          int* __restrict__ fill, float4* __restrict__ edge) {
    int e = blockIdx.x * blockDim.x + threadIdx.x;
    if (e >= NE) return;
    int t = tgt[e];
    int p = off[t] + atomicAdd(&fill[t], 1);
    float4 r;
    r.x = to_f(ea[e * 3 + 0]);
    r.y = to_f(ea[e * 3 + 1]);
    r.z = to_f(ea[e * 3 + 2]);
    r.w = __int_as_float(src[e]);
    edge[p] = r;
}

__global__ void fill_kernel(const int* __restrict__ src, const int* __restrict__ tgt,
                            const void* ea, const int* __restrict__ off,
                            const int* __restrict__ flagp,
                            int* __restrict__ fill, float4* __restrict__ edge) {
    if (*flagp) fill_impl<float>(src, tgt, (const float*)ea, off, fill, edge);
    else        fill_impl<bf16>(src, tgt, (const bf16*)ea, off, fill, edge);
}

// --- linear_pre: W staged once per block, NPB node rows --------------------
template <typename T>
__device__ __forceinline__ void pre_impl(float* __restrict__ Wl, float* __restrict__ xs,
                                         const T* __restrict__ x, const T* __restrict__ w,
                                         const T* __restrict__ b, float* __restrict__ h) {
    int tid = threadIdx.x, fo = tid & 63, wv = tid >> 6;
    int nb = blockIdx.x * NPB;
    for (int i = tid; i < IND * C; i += 256) Wl[i] = to_f(w[i]);
    for (int i = tid; i < NPB * IND; i += 256) xs[i] = to_f(x[nb * IND + i]);  // contiguous
    __syncthreads();
    float bb = to_f(b[fo]);
#pragma unroll
    for (int q = 0; q < NPB / 4; ++q) {
        int m = wv * (NPB / 4) + q;
        float acc = bb;
#pragma unroll 8
        for (int fi = 0; fi < IND; ++fi)
            acc += xs[m * IND + fi] * Wl[fi * C + fo];
        h[(nb + m) * C + fo] = acc;
    }
}

__global__ __launch_bounds__(256) void pre_kernel(const void* x, const void* w, const void* b,
                                                  const int* __restrict__ flagp, float* __restrict__ h) {
    __shared__ float Wl[IND * C];     // 32 KB
    __shared__ float xs[NPB * IND];   //  8 KB
    if (*flagp) pre_impl<float>(Wl, xs, (const float*)x, (const float*)w, (const float*)b, h);
    else        pre_impl<bf16>(Wl, xs, (const bf16*)x, (const bf16*)w, (const bf16*)b, h);
}

// --- aggregation: one wave per node, no atomics, no LDS --------------------
// s[n, c*64+f] = inv[n] * sum_{edges e->n} ea_c[e] * h[src[e], f]
__global__ __launch_bounds__(256) void agg_kernel(const float* __restrict__ h,
                                                  const float4* __restrict__ edge,
                                                  const int* __restrict__ off,
                                                  const float* __restrict__ inv,
                                                  float* __restrict__ s) {
    int f = threadIdx.x & 63;
    int n = blockIdx.x * 4 + (threadIdx.x >> 6);
    int beg = off[n], end = off[n + 1];
    float a0 = 0.f, a1 = 0.f, a2 = 0.f;
    int e = beg;
    for (; e + 2 <= end; e += 2) {
        float4 r0 = edge[e];
        float4 r1 = edge[e + 1];
        float h0 = h[(__float_as_int(r0.w) << 6) + f];
        float h1 = h[(__float_as_int(r1.w) << 6) + f];
        a0 += r0.x * h0; a1 += r0.y * h0; a2 += r0.z * h0;
        a0 += r1.x * h1; a1 += r1.y * h1; a2 += r1.z * h1;
    }
    if (e < end) {
        float4 r = edge[e];
        float hv = h[(__float_as_int(r.w) << 6) + f];
        a0 += r.x * hv; a1 += r.y * hv; a2 += r.z * hv;
    }
    float iv = inv[n];
    float* so = s + n * 192;
    so[f] = a0 * iv; so[64 + f] = a1 * iv; so[128 + f] = a2 * iv;
}

// --- dense: out = S @ W + b; MODE 0: relu -> H; MODE 1: L2-norm -> out -----
template <typename T, int MODE>
__device__ __forceinline__ void gemm_impl(float* __restrict__ Wl, float* __restrict__ srow,
                                          const float* __restrict__ s, const T* __restrict__ w,
                                          const T* __restrict__ b, float* __restrict__ hout,
                                          T* __restrict__ out) {
    int tid = threadIdx.x, fo = tid & 63, wv = tid >> 6;
    int nb = blockIdx.x * NPB;
    for (int i = tid; i < 192 * C; i += 256) Wl[i] = to_f(w[i]);
    for (int i = tid; i < NPB * 192; i += 256) srow[i] = s[nb * 192 + i];  // contiguous
    __syncthreads();
    float bb = to_f(b[fo]);
#pragma unroll
    for (int q = 0; q < NPB / 4; ++q) {
        int m = wv * (NPB / 4) + q;
        float acc = bb;
#pragma unroll 8
        for (int k = 0; k < 192; ++k)
            acc += srow[m * 192 + k] * Wl[k * C + fo];
        if constexpr (MODE == 0) {
            hout[(nb + m) * C + fo] = fmaxf(acc, 0.0f);
        } else {
            float sq = acc * acc;
#pragma unroll
            for (int o = 32; o; o >>= 1) sq += __shfl_xor(sq, o, 64);
            float r = acc / fmaxf(sqrtf(sq), 1e-12f);
            if constexpr (sizeof(T) == 2) out[(nb + m) * C + fo] = __float2bfloat16(r);
            else                          out[(nb + m) * C + fo] = r;
        }
    }
}

__global__ __launch_bounds__(256) void gemm_relu(const float* __restrict__ s, const void* w,
                                                 const void* b, const int* __restrict__ flagp,
                                                 float* __restrict__ hout) {
    __shared__ float Wl[192 * C];     // 48 KB
    __shared__ float srow[NPB * 192]; // 12 KB
    if (*flagp) gemm_impl<float, 0>(Wl, srow, s, (const float*)w, (const float*)b, hout, (float*)nullptr);
    else        gemm_impl<bf16, 0>(Wl, srow, s, (const bf16*)w, (const bf16*)b, hout, (bf16*)nullptr);
}

__global__ __launch_bounds__(256) void gemm_norm(const float* __restrict__ s, const void* w,
                                                 const void* b, const int* __restrict__ flagp,
                                                 void* out) {
    __shared__ float Wl[192 * C];
    __shared__ float srow[NPB * 192];
    if (*flagp) gemm_impl<float, 1>(Wl, srow, s, (const float*)w, (const float*)b, nullptr, (float*)out);
    else        gemm_impl<bf16, 1>(Wl, srow, s, (const bf16*)w, (const bf16*)b, nullptr, (bf16*)out);
}

extern "C" void kernel_launch(void* const* d_in, const int* in_sizes, int n_in,
                              void* d_out, int out_size, void* d_ws, size_t ws_size,
                              hipStream_t stream) {
    const void* x     = d_in[0];
    const int*  ei    = (const int*)d_in[1];
    const void* ea    = d_in[2];
    const void* pre_w = d_in[3];
    const void* pre_b = d_in[4];
    const void* W[3]  = {d_in[5], d_in[7], d_in[9]};
    const void* B[3]  = {d_in[6], d_in[8], d_in[10]};
    const int* src = ei;
    const int* tgt = ei + NE;

    // ws layout: EDGE f4[NE] | H[NN*64] | S[NN*192] | OFF[NN+1] | CNT[NN] | FILL[NN] | INV[NN] | FLAG
    float4* EDGE = (float4*)d_ws;                 // 12.8 MB
    float*  H    = (float*)(EDGE + NE);           // 12.8 MB
    float*  S    = H + (size_t)NN * C;            // 38.4 MB
    int*    OFF  = (int*)(S + (size_t)NN * 192);
    int*    CNT  = OFF + NN + 1;
    int*    FILL = CNT + NN;
    float*  INV  = (float*)(FILL + NN);
    int*    FLAG = (int*)(INV + NN);

    detect_kernel<<<1, 64, 0, stream>>>((const unsigned*)x, FLAG);
    hipMemsetAsync(CNT, 0, 2 * NN * sizeof(int), stream);   // zeros CNT and FILL
    count_kernel<<<(NE + 255) / 256, 256, 0, stream>>>(tgt, CNT);
    scan_kernel<<<1, 1024, 0, stream>>>(CNT, OFF, INV);
    fill_kernel<<<(NE + 255) / 256, 256, 0, stream>>>(src, tgt, ea, OFF, FLAG, FILL, EDGE);
    pre_kernel<<<NN / NPB, 256, 0, stream>>>(x, pre_w, pre_b, FLAG, H);

    for (int l = 0; l < 3; ++l) {
        agg_kernel<<<NN / 4, 256, 0, stream>>>(H, EDGE, OFF, INV, S);
        if (l < 2)
            gemm_relu<<<NN / NPB, 256, 0, stream>>>(S, W[l], B[l], FLAG, H);
        else
            gemm_norm<<<NN / NPB, 256, 0, stream>>>(S, W[l], B[l], FLAG, d_out);
    }
}

// Round 5
// 515.677 us; speedup vs baseline: 2.0307x; 1.3615x over previous
//
#include <hip/hip_runtime.h>
#include <hip/hip_bf16.h>

#define NN 50000
#define NE 800000
#define IND 128
#define C 64     // FEAT = HID = OUT

typedef __hip_bfloat16 bf16;

__device__ __forceinline__ float to_f(float v) { return v; }
__device__ __forceinline__ float to_f(bf16 v)  { return __bfloat162float(v); }

// --- dtype detect: float inputs fp32 (flag=1) or bf16 (flag=0)? ------------
__global__ void detect_kernel(const unsigned* __restrict__ xu, int* __restrict__ flag) {
    int lane = threadIdx.x;
    unsigned u  = xu[lane];
    unsigned ex = (u >> 7) & 0xFF;
    int vote = (ex >= 90 && ex <= 144) ? 1 : 0;
#pragma unroll
    for (int off = 32; off; off >>= 1) vote += __shfl_xor(vote, off, 64);
    if (lane == 0) *flag = (vote < 40) ? 1 : 0;
}

// --- degree histogram ------------------------------------------------------
__global__ void count_kernel(const int* __restrict__ tgt, int* __restrict__ cnt) {
    int e = blockIdx.x * blockDim.x + threadIdx.x;
    if (e < NE) atomicAdd(&cnt[tgt[e]], 1);
}

// --- single-block exclusive scan over cnt -> off; also inv = 1/max(cnt,1) --
__global__ __launch_bounds__(1024) void scan_kernel(const int* __restrict__ cnt,
                                                    int* __restrict__ off,
                                                    float* __restrict__ inv) {
    __shared__ int wsum[16];
    __shared__ int carry;
    int tid = threadIdx.x, lane = tid & 63, wv = tid >> 6;
    if (tid == 0) carry = 0;
    __syncthreads();
    for (int base = 0; base < NN; base += 1024) {
        int i = base + tid;
        int v = (i < NN) ? cnt[i] : 0;
        int incl = v;
#pragma unroll
        for (int d = 1; d < 64; d <<= 1) { int t = __shfl_up(incl, d, 64); if (lane >= d) incl += t; }
        if (lane == 63) wsum[wv] = incl;
        __syncthreads();
        if (wv == 0) {
            int ws = (lane < 16) ? wsum[lane] : 0;
#pragma unroll
            for (int d = 1; d < 16; d <<= 1) { int t = __shfl_up(ws, d, 64); if (lane >= d) ws += t; }
            if (lane < 16) wsum[lane] = ws;
        }
        __syncthreads();
        int wbase = (wv == 0) ? 0 : wsum[wv - 1];
        int excl = carry + wbase + incl - v;
        if (i < NN) { off[i] = excl; inv[i] = 1.0f / fmaxf((float)v, 1.0f); }
        __syncthreads();
        if (tid == 1023) carry += wsum[15];
        __syncthreads();
    }
    if (tid == 0) off[NN] = NE;
}

// --- place edges sorted by target: record = {e0,e1,e2, src} ----------------
template <typename T>
__device__ __forceinline__ void fill_impl(const int* __restrict__ src, const int* __restrict__ tgt,
                                          const T* __restrict__ ea, const int* __restrict__ off,
                                          int* __restrict__ fill, float4* __restrict__ edge) {
    int e = blockIdx.x * blockDim.x + threadIdx.x;
    if (e >= NE) return;
    int t = tgt[e];
    int p = off[t] + atomicAdd(&fill[t], 1);
    float4 r;
    r.x = to_f(ea[e * 3 + 0]);
    r.y = to_f(ea[e * 3 + 1]);
    r.z = to_f(ea[e * 3 + 2]);
    r.w = __int_as_float(src[e]);
    edge[p] = r;
}

__global__ void fill_kernel(const int* __restrict__ src, const int* __restrict__ tgt,
                            const void* ea, const int* __restrict__ off,
                            const int* __restrict__ flagp,
                            int* __restrict__ fill, float4* __restrict__ edge) {
    if (*flagp) fill_impl<float>(src, tgt, (const float*)ea, off, fill, edge);
    else        fill_impl<bf16>(src, tgt, (const bf16*)ea, off, fill, edge);
}

// --- linear_pre: 64 rows/block, 4x4 register tile per thread ---------------
// Xl[row][k] stride 132: rows 16 apart -> banks +4 apart; 16B-aligned rows.
template <typename T>
__device__ __forceinline__ void pre_impl(float (*Xl)[132], const T* __restrict__ x,
                                         const T* __restrict__ w, const T* __restrict__ b,
                                         float* __restrict__ h) {
    int tid = threadIdx.x;
    int nb  = blockIdx.x * 64;
    // stage 64 rows x 128 cols, converting to fp32; 8B/16B vector loads
    if constexpr (sizeof(T) == 2) {
        const ushort4* xg = (const ushort4*)(x + (size_t)nb * IND);
        for (int j = tid; j < 64 * 32; j += 256) {           // 32 ushort4 per row
            int row = j >> 5, kk = (j & 31) * 4;
            ushort4 u = (nb + row < NN) ? xg[j] : make_ushort4(0, 0, 0, 0);
            Xl[row][kk]     = __uint_as_float((unsigned)u.x << 16);
            Xl[row][kk + 1] = __uint_as_float((unsigned)u.y << 16);
            Xl[row][kk + 2] = __uint_as_float((unsigned)u.z << 16);
            Xl[row][kk + 3] = __uint_as_float((unsigned)u.w << 16);
        }
    } else {
        const float4* xg = (const float4*)(x + (size_t)nb * IND);
        for (int j = tid; j < 64 * 32; j += 256) {
            int row = j >> 5, kk = (j & 31) * 4;
            float4 v = (nb + row < NN) ? xg[j] : make_float4(0.f, 0.f, 0.f, 0.f);
            Xl[row][kk] = v.x; Xl[row][kk + 1] = v.y; Xl[row][kk + 2] = v.z; Xl[row][kk + 3] = v.w;
        }
    }
    __syncthreads();
    int tx = tid & 15, ty = tid >> 4, c0 = tx * 4;
    float acc[4][4];
#pragma unroll
    for (int r = 0; r < 4; ++r)
#pragma unroll
        for (int j = 0; j < 4; ++j) acc[r][j] = to_f(b[c0 + j]);
    for (int k = 0; k < IND; k += 4) {
#pragma unroll
        for (int kk = 0; kk < 4; ++kk) {
            float wv[4];
#pragma unroll
            for (int j = 0; j < 4; ++j) wv[j] = to_f(w[(k + kk) * C + c0 + j]);
#pragma unroll
            for (int r = 0; r < 4; ++r) {
                float sv = Xl[ty + 16 * r][k + kk];
#pragma unroll
                for (int j = 0; j < 4; ++j) acc[r][j] += sv * wv[j];
            }
        }
    }
#pragma unroll
    for (int r = 0; r < 4; ++r) {
        int row = nb + ty + 16 * r;
        if (row < NN) {
            float4 v = make_float4(acc[r][0], acc[r][1], acc[r][2], acc[r][3]);
            *(float4*)(h + (size_t)row * C + c0) = v;
        }
    }
}

__global__ __launch_bounds__(256) void pre_kernel(const void* x, const void* w, const void* b,
                                                  const int* __restrict__ flagp, float* __restrict__ h) {
    __shared__ float Xl[64][132];   // ~33.8 KB
    if (*flagp) pre_impl<float>(Xl, (const float*)x, (const float*)w, (const float*)b, h);
    else        pre_impl<bf16>(Xl, (const bf16*)x, (const bf16*)w, (const bf16*)b, h);
}

// --- aggregation: one wave per node, no atomics, no LDS --------------------
__global__ __launch_bounds__(256) void agg_kernel(const float* __restrict__ h,
                                                  const float4* __restrict__ edge,
                                                  const int* __restrict__ off,
                                                  const float* __restrict__ inv,
                                                  float* __restrict__ s) {
    int f = threadIdx.x & 63;
    int n = blockIdx.x * 4 + (threadIdx.x >> 6);
    int beg = off[n], end = off[n + 1];
    float a0 = 0.f, a1 = 0.f, a2 = 0.f;
    int e = beg;
    for (; e + 2 <= end; e += 2) {
        float4 r0 = edge[e];
        float4 r1 = edge[e + 1];
        float h0 = h[(__float_as_int(r0.w) << 6) + f];
        float h1 = h[(__float_as_int(r1.w) << 6) + f];
        a0 += r0.x * h0; a1 += r0.y * h0; a2 += r0.z * h0;
        a0 += r1.x * h1; a1 += r1.y * h1; a2 += r1.z * h1;
    }
    if (e < end) {
        float4 r = edge[e];
        float hv = h[(__float_as_int(r.w) << 6) + f];
        a0 += r.x * hv; a1 += r.y * hv; a2 += r.z * hv;
    }
    float iv = inv[n];
    float* so = s + n * 192;
    so[f] = a0 * iv; so[64 + f] = a1 * iv; so[128 + f] = a2 * iv;
}

// --- dense: out = S @ W + b; MODE 0: relu -> H; MODE 1: L2-norm -> out -----
// 64 rows/block, 4x4 register tile; Sl stride 196 (bank +4/row, 16B aligned).
template <typename T, int MODE>
__device__ __forceinline__ void gemm_impl(float (*Sl)[196], const float* __restrict__ s,
                                          const T* __restrict__ w, const T* __restrict__ b,
                                          float* __restrict__ hout, T* __restrict__ out) {
    int tid = threadIdx.x;
    int nb  = blockIdx.x * 64;
    const float4* sg = (const float4*)(s + (size_t)nb * 192);
    for (int j = tid; j < 64 * 48; j += 256) {               // 48 float4 per row
        int row = j / 48, kk = (j % 48) * 4;
        float4 v = (nb + row < NN) ? sg[j] : make_float4(0.f, 0.f, 0.f, 0.f);
        Sl[row][kk] = v.x; Sl[row][kk + 1] = v.y; Sl[row][kk + 2] = v.z; Sl[row][kk + 3] = v.w;
    }
    __syncthreads();
    int tx = tid & 15, ty = tid >> 4, c0 = tx * 4;
    float acc[4][4];
#pragma unroll
    for (int r = 0; r < 4; ++r)
#pragma unroll
        for (int j = 0; j < 4; ++j) acc[r][j] = to_f(b[c0 + j]);
    for (int k = 0; k < 192; k += 4) {
#pragma unroll
        for (int kk = 0; kk < 4; ++kk) {
            float wv[4];
#pragma unroll
            for (int j = 0; j < 4; ++j) wv[j] = to_f(w[(k + kk) * C + c0 + j]);
#pragma unroll
            for (int r = 0; r < 4; ++r) {
                float sv = Sl[ty + 16 * r][k + kk];
#pragma unroll
                for (int j = 0; j < 4; ++j) acc[r][j] += sv * wv[j];
            }
        }
    }
#pragma unroll
    for (int r = 0; r < 4; ++r) {
        int row = nb + ty + 16 * r;
        if constexpr (MODE == 0) {
            if (row < NN) {
                float4 v = make_float4(fmaxf(acc[r][0], 0.f), fmaxf(acc[r][1], 0.f),
                                       fmaxf(acc[r][2], 0.f), fmaxf(acc[r][3], 0.f));
                *(float4*)(hout + (size_t)row * C + c0) = v;
            }
        } else {
            float sq = acc[r][0] * acc[r][0] + acc[r][1] * acc[r][1]
                     + acc[r][2] * acc[r][2] + acc[r][3] * acc[r][3];
#pragma unroll
            for (int o = 1; o < 16; o <<= 1) sq += __shfl_xor(sq, o, 64);
            float innorm = 1.0f / fmaxf(sqrtf(sq), 1e-12f);
            if (row < NN) {
#pragma unroll
                for (int j = 0; j < 4; ++j) {
                    float rv = acc[r][j] * innorm;
                    if constexpr (sizeof(T) == 2) out[(size_t)row * C + c0 + j] = __float2bfloat16(rv);
                    else                          out[(size_t)row * C + c0 + j] = rv;
                }
            }
        }
    }
}

__global__ __launch_bounds__(256) void gemm_relu(const float* __restrict__ s, const void* w,
                                                 const void* b, const int* __restrict__ flagp,
                                                 float* __restrict__ hout) {
    __shared__ float Sl[64][196];   // ~50 KB
    if (*flagp) gemm_impl<float, 0>(Sl, s, (const float*)w, (const float*)b, hout, (float*)nullptr);
    else        gemm_impl<bf16, 0>(Sl, s, (const bf16*)w, (const bf16*)b, hout, (bf16*)nullptr);
}

__global__ __launch_bounds__(256) void gemm_norm(const float* __restrict__ s, const void* w,
                                                 const void* b, const int* __restrict__ flagp,
                                                 void* out) {
    __shared__ float Sl[64][196];
    if (*flagp) gemm_impl<float, 1>(Sl, s, (const float*)w, (const float*)b, nullptr, (float*)out);
    else        gemm_impl<bf16, 1>(Sl, s, (const bf16*)w, (const bf16*)b, nullptr, (bf16*)out);
}

extern "C" void kernel_launch(void* const* d_in, const int* in_sizes, int n_in,
                              void* d_out, int out_size, void* d_ws, size_t ws_size,
                              hipStream_t stream) {
    const void* x     = d_in[0];
    const int*  ei    = (const int*)d_in[1];
    const void* ea    = d_in[2];
    const void* pre_w = d_in[3];
    const void* pre_b = d_in[4];
    const void* W[3]  = {d_in[5], d_in[7], d_in[9]};
    const void* B[3]  = {d_in[6], d_in[8], d_in[10]};
    const int* src = ei;
    const int* tgt = ei + NE;

    // ws layout: EDGE f4[NE] | H[NN*64] | S[NN*192] | OFF[NN+1] | CNT[NN] | FILL[NN] | INV[NN] | FLAG
    float4* EDGE = (float4*)d_ws;
    float*  H    = (float*)(EDGE + NE);
    float*  S    = H + (size_t)NN * C;
    int*    OFF  = (int*)(S + (size_t)NN * 192);
    int*    CNT  = OFF + NN + 1;
    int*    FILL = CNT + NN;
    float*  INV  = (float*)(FILL + NN);
    int*    FLAG = (int*)(INV + NN);

    detect_kernel<<<1, 64, 0, stream>>>((const unsigned*)x, FLAG);
    hipMemsetAsync(CNT, 0, 2 * NN * sizeof(int), stream);   // zeros CNT and FILL
    count_kernel<<<(NE + 255) / 256, 256, 0, stream>>>(tgt, CNT);
    scan_kernel<<<1, 1024, 0, stream>>>(CNT, OFF, INV);
    fill_kernel<<<(NE + 255) / 256, 256, 0, stream>>>(src, tgt, ea, OFF, FLAG, FILL, EDGE);
    pre_kernel<<<(NN + 63) / 64, 256, 0, stream>>>(x, pre_w, pre_b, FLAG, H);

    for (int l = 0; l < 3; ++l) {
        agg_kernel<<<NN / 4, 256, 0, stream>>>(H, EDGE, OFF, INV, S);
        if (l < 2)
            gemm_relu<<<(NN + 63) / 64, 256, 0, stream>>>(S, W[l], B[l], FLAG, H);
        else
            gemm_norm<<<(NN + 63) / 64, 256, 0, stream>>>(S, W[l], B[l], FLAG, d_out);
    }
}

// Round 6
// 403.970 us; speedup vs baseline: 2.5923x; 1.2765x over previous
//
#include <hip/hip_runtime.h>
#include <hip/hip_bf16.h>

#define NN 50000
#define NE 800000
#define IND 128
#define C 64     // FEAT = HID = OUT

typedef __hip_bfloat16 bf16;

__device__ __forceinline__ float to_f(float v) { return v; }
__device__ __forceinline__ float to_f(bf16 v)  { return __bfloat162float(v); }

// bf16 <-> fp32 raw helpers (H is stored as ushort bf16 internally)
__device__ __forceinline__ unsigned short f2b(float v) {
    unsigned u = __float_as_uint(v);
    return (unsigned short)((u + 0x7FFFu + ((u >> 16) & 1u)) >> 16);   // RNE
}
__device__ __forceinline__ float b2f(unsigned short u) {
    return __uint_as_float((unsigned)u << 16);
}

// --- dtype detect: float inputs fp32 (flag=1) or bf16 (flag=0)? ------------
__global__ void detect_kernel(const unsigned* __restrict__ xu, int* __restrict__ flag) {
    int lane = threadIdx.x;
    unsigned u  = xu[lane];
    unsigned ex = (u >> 7) & 0xFF;
    int vote = (ex >= 90 && ex <= 144) ? 1 : 0;
#pragma unroll
    for (int off = 32; off; off >>= 1) vote += __shfl_xor(vote, off, 64);
    if (lane == 0) *flag = (vote < 40) ? 1 : 0;
}

// --- degree histogram ------------------------------------------------------
__global__ void count_kernel(const int* __restrict__ tgt, int* __restrict__ cnt) {
    int e = blockIdx.x * blockDim.x + threadIdx.x;
    if (e < NE) atomicAdd(&cnt[tgt[e]], 1);
}

// --- single-block exclusive scan (4 counts/thread) -> off; inv = 1/max(c,1)
__global__ __launch_bounds__(1024) void scan_kernel(const int4* __restrict__ cnt4,
                                                    int* __restrict__ off,
                                                    float* __restrict__ inv) {
    __shared__ int wsum[16];
    __shared__ int carry_s;
    int tid = threadIdx.x, lane = tid & 63, wv = tid >> 6;
    if (tid == 0) carry_s = 0;
    __syncthreads();
    const int NV = NN / 4;   // 12500
    for (int base = 0; base < NV; base += 1024) {
        int i = base + tid;
        int4 v = (i < NV) ? cnt4[i] : make_int4(0, 0, 0, 0);
        int tot = v.x + v.y + v.z + v.w;
        int incl = tot;
#pragma unroll
        for (int d = 1; d < 64; d <<= 1) { int t = __shfl_up(incl, d, 64); if (lane >= d) incl += t; }
        if (lane == 63) wsum[wv] = incl;
        __syncthreads();
        if (wv == 0) {
            int ws = (lane < 16) ? wsum[lane] : 0;
#pragma unroll
            for (int d = 1; d < 16; d <<= 1) { int t = __shfl_up(ws, d, 64); if (lane >= d) ws += t; }
            if (lane < 16) wsum[lane] = ws;
        }
        __syncthreads();
        int wbase = (wv == 0) ? 0 : wsum[wv - 1];
        int excl = carry_s + wbase + incl - tot;
        if (i < NV) {
            off[4 * i]     = excl;
            off[4 * i + 1] = excl + v.x;
            off[4 * i + 2] = excl + v.x + v.y;
            off[4 * i + 3] = excl + v.x + v.y + v.z;
            inv[4 * i]     = 1.0f / fmaxf((float)v.x, 1.0f);
            inv[4 * i + 1] = 1.0f / fmaxf((float)v.y, 1.0f);
            inv[4 * i + 2] = 1.0f / fmaxf((float)v.z, 1.0f);
            inv[4 * i + 3] = 1.0f / fmaxf((float)v.w, 1.0f);
        }
        __syncthreads();
        if (tid == 1023) carry_s += wsum[15];
        __syncthreads();
    }
    if (tid == 0) off[NN] = NE;
}

// --- place edges sorted by target: record = {e0,e1,e2, src} ----------------
template <typename T>
__device__ __forceinline__ void fill_impl(const int* __restrict__ src, const int* __restrict__ tgt,
                                          const T* __restrict__ ea, const int* __restrict__ off,
                                          int* __restrict__ fill, float4* __restrict__ edge) {
    int e = blockIdx.x * blockDim.x + threadIdx.x;
    if (e >= NE) return;
    int t = tgt[e];
    int p = off[t] + atomicAdd(&fill[t], 1);
    float4 r;
    r.x = to_f(ea[e * 3 + 0]);
    r.y = to_f(ea[e * 3 + 1]);
    r.z = to_f(ea[e * 3 + 2]);
    r.w = __int_as_float(src[e]);
    edge[p] = r;
}

__global__ void fill_kernel(const int* __restrict__ src, const int* __restrict__ tgt,
                            const void* ea, const int* __restrict__ off,
                            const int* __restrict__ flagp,
                            int* __restrict__ fill, float4* __restrict__ edge) {
    if (*flagp) fill_impl<float>(src, tgt, (const float*)ea, off, fill, edge);
    else        fill_impl<bf16>(src, tgt, (const bf16*)ea, off, fill, edge);
}

// --- linear_pre: 64 rows/block, 4x4 register tile; H stored bf16 -----------
template <typename T>
__device__ __forceinline__ void pre_impl(float (*Xl)[132], const T* __restrict__ x,
                                         const T* __restrict__ w, const T* __restrict__ b,
                                         unsigned short* __restrict__ h) {
    int tid = threadIdx.x;
    int nb  = blockIdx.x * 64;
    if constexpr (sizeof(T) == 2) {
        const ushort4* xg = (const ushort4*)(x + (size_t)nb * IND);
        for (int j = tid; j < 64 * 32; j += 256) {
            int row = j >> 5, kk = (j & 31) * 4;
            ushort4 u = (nb + row < NN) ? xg[j] : make_ushort4(0, 0, 0, 0);
            Xl[row][kk]     = b2f(u.x);
            Xl[row][kk + 1] = b2f(u.y);
            Xl[row][kk + 2] = b2f(u.z);
            Xl[row][kk + 3] = b2f(u.w);
        }
    } else {
        const float4* xg = (const float4*)(x + (size_t)nb * IND);
        for (int j = tid; j < 64 * 32; j += 256) {
            int row = j >> 5, kk = (j & 31) * 4;
            float4 v = (nb + row < NN) ? xg[j] : make_float4(0.f, 0.f, 0.f, 0.f);
            Xl[row][kk] = v.x; Xl[row][kk + 1] = v.y; Xl[row][kk + 2] = v.z; Xl[row][kk + 3] = v.w;
        }
    }
    __syncthreads();
    int tx = tid & 15, ty = tid >> 4, c0 = tx * 4;
    float acc[4][4];
#pragma unroll
    for (int r = 0; r < 4; ++r)
#pragma unroll
        for (int j = 0; j < 4; ++j) acc[r][j] = to_f(b[c0 + j]);
    for (int k = 0; k < IND; k += 4) {
#pragma unroll
        for (int kk = 0; kk < 4; ++kk) {
            float wv[4];
#pragma unroll
            for (int j = 0; j < 4; ++j) wv[j] = to_f(w[(k + kk) * C + c0 + j]);
#pragma unroll
            for (int r = 0; r < 4; ++r) {
                float sv = Xl[ty + 16 * r][k + kk];
#pragma unroll
                for (int j = 0; j < 4; ++j) acc[r][j] += sv * wv[j];
            }
        }
    }
#pragma unroll
    for (int r = 0; r < 4; ++r) {
        int row = nb + ty + 16 * r;
        if (row < NN) {
            ushort4 uv = make_ushort4(f2b(acc[r][0]), f2b(acc[r][1]), f2b(acc[r][2]), f2b(acc[r][3]));
            *(ushort4*)(h + (size_t)row * C + c0) = uv;
        }
    }
}

__global__ __launch_bounds__(256) void pre_kernel(const void* x, const void* w, const void* b,
                                                  const int* __restrict__ flagp,
                                                  unsigned short* __restrict__ h) {
    __shared__ float Xl[64][132];
    if (*flagp) pre_impl<float>(Xl, (const float*)x, (const float*)w, (const float*)b, h);
    else        pre_impl<bf16>(Xl, (const bf16*)x, (const bf16*)w, (const bf16*)b, h);
}

// --- aggregation: one wave/node, software-pipelined, bf16 h gathers --------
__global__ __launch_bounds__(256) void agg_kernel(const unsigned short* __restrict__ hb,
                                                  const float4* __restrict__ edge,
                                                  const int* __restrict__ off,
                                                  const float* __restrict__ inv,
                                                  float* __restrict__ s) {
    int f = threadIdx.x & 63;
    int n = blockIdx.x * 4 + (threadIdx.x >> 6);
    int beg = __builtin_amdgcn_readfirstlane(off[n]);
    int end = __builtin_amdgcn_readfirstlane(off[n + 1]);
    float a0 = 0.f, a1 = 0.f, a2 = 0.f;
    int e = beg;
    int m4 = beg + ((end - beg) & ~3);
    if (e < m4) {
        float4 c0 = edge[e], c1 = edge[e + 1], c2 = edge[e + 2], c3 = edge[e + 3];
        e += 4;
        for (; e < m4; e += 4) {
            float h0 = b2f(hb[(__float_as_int(c0.w) << 6) + f]);
            float h1 = b2f(hb[(__float_as_int(c1.w) << 6) + f]);
            float h2 = b2f(hb[(__float_as_int(c2.w) << 6) + f]);
            float h3 = b2f(hb[(__float_as_int(c3.w) << 6) + f]);
            float4 n0 = edge[e], n1 = edge[e + 1], n2 = edge[e + 2], n3 = edge[e + 3];
            a0 += c0.x * h0; a1 += c0.y * h0; a2 += c0.z * h0;
            a0 += c1.x * h1; a1 += c1.y * h1; a2 += c1.z * h1;
            a0 += c2.x * h2; a1 += c2.y * h2; a2 += c2.z * h2;
            a0 += c3.x * h3; a1 += c3.y * h3; a2 += c3.z * h3;
            c0 = n0; c1 = n1; c2 = n2; c3 = n3;
        }
        float h0 = b2f(hb[(__float_as_int(c0.w) << 6) + f]);
        float h1 = b2f(hb[(__float_as_int(c1.w) << 6) + f]);
        float h2 = b2f(hb[(__float_as_int(c2.w) << 6) + f]);
        float h3 = b2f(hb[(__float_as_int(c3.w) << 6) + f]);
        a0 += c0.x * h0; a1 += c0.y * h0; a2 += c0.z * h0;
        a0 += c1.x * h1; a1 += c1.y * h1; a2 += c1.z * h1;
        a0 += c2.x * h2; a1 += c2.y * h2; a2 += c2.z * h2;
        a0 += c3.x * h3; a1 += c3.y * h3; a2 += c3.z * h3;
    }
    for (; e < end; ++e) {
        float4 r = edge[e];
        float hv = b2f(hb[(__float_as_int(r.w) << 6) + f]);
        a0 += r.x * hv; a1 += r.y * hv; a2 += r.z * hv;
    }
    float iv = inv[n];
    float* so = s + n * 192;
    so[f] = a0 * iv; so[64 + f] = a1 * iv; so[128 + f] = a2 * iv;
}

// --- dense: out = S @ W + b; MODE 0: relu -> H(bf16); MODE 1: L2-norm ------
template <typename T, int MODE>
__device__ __forceinline__ void gemm_impl(float (*Sl)[196], const float* __restrict__ s,
                                          const T* __restrict__ w, const T* __restrict__ b,
                                          unsigned short* __restrict__ hout, T* __restrict__ out) {
    int tid = threadIdx.x;
    int nb  = blockIdx.x * 64;
    const float4* sg = (const float4*)(s + (size_t)nb * 192);
    for (int j = tid; j < 64 * 48; j += 256) {
        int row = j / 48, kk = (j % 48) * 4;
        float4 v = (nb + row < NN) ? sg[j] : make_float4(0.f, 0.f, 0.f, 0.f);
        Sl[row][kk] = v.x; Sl[row][kk + 1] = v.y; Sl[row][kk + 2] = v.z; Sl[row][kk + 3] = v.w;
    }
    __syncthreads();
    int tx = tid & 15, ty = tid >> 4, c0 = tx * 4;
    float acc[4][4];
#pragma unroll
    for (int r = 0; r < 4; ++r)
#pragma unroll
        for (int j = 0; j < 4; ++j) acc[r][j] = to_f(b[c0 + j]);
    for (int k = 0; k < 192; k += 4) {
#pragma unroll
        for (int kk = 0; kk < 4; ++kk) {
            float wv[4];
#pragma unroll
            for (int j = 0; j < 4; ++j) wv[j] = to_f(w[(k + kk) * C + c0 + j]);
#pragma unroll
            for (int r = 0; r < 4; ++r) {
                float sv = Sl[ty + 16 * r][k + kk];
#pragma unroll
                for (int j = 0; j < 4; ++j) acc[r][j] += sv * wv[j];
            }
        }
    }
#pragma unroll
    for (int r = 0; r < 4; ++r) {
        int row = nb + ty + 16 * r;
        if constexpr (MODE == 0) {
            if (row < NN) {
                ushort4 uv = make_ushort4(f2b(fmaxf(acc[r][0], 0.f)), f2b(fmaxf(acc[r][1], 0.f)),
                                          f2b(fmaxf(acc[r][2], 0.f)), f2b(fmaxf(acc[r][3], 0.f)));
                *(ushort4*)(hout + (size_t)row * C + c0) = uv;
            }
        } else {
            float sq = acc[r][0] * acc[r][0] + acc[r][1] * acc[r][1]
                     + acc[r][2] * acc[r][2] + acc[r][3] * acc[r][3];
#pragma unroll
            for (int o = 1; o < 16; o <<= 1) sq += __shfl_xor(sq, o, 64);
            float innorm = 1.0f / fmaxf(sqrtf(sq), 1e-12f);
            if (row < NN) {
#pragma unroll
                for (int j = 0; j < 4; ++j) {
                    float rv = acc[r][j] * innorm;
                    if constexpr (sizeof(T) == 2) out[(size_t)row * C + c0 + j] = __float2bfloat16(rv);
                    else                          out[(size_t)row * C + c0 + j] = rv;
                }
            }
        }
    }
}

__global__ __launch_bounds__(256) void gemm_relu(const float* __restrict__ s, const void* w,
                                                 const void* b, const int* __restrict__ flagp,
                                                 unsigned short* __restrict__ hout) {
    __shared__ float Sl[64][196];
    if (*flagp) gemm_impl<float, 0>(Sl, s, (const float*)w, (const float*)b, hout, (float*)nullptr);
    else        gemm_impl<bf16, 0>(Sl, s, (const bf16*)w, (const bf16*)b, hout, (bf16*)nullptr);
}

__global__ __launch_bounds__(256) void gemm_norm(const float* __restrict__ s, const void* w,
                                                 const void* b, const int* __restrict__ flagp,
                                                 void* out) {
    __shared__ float Sl[64][196];
    if (*flagp) gemm_impl<float, 1>(Sl, s, (const float*)w, (const float*)b, nullptr, (float*)out);
    else        gemm_impl<bf16, 1>(Sl, s, (const bf16*)w, (const bf16*)b, nullptr, (bf16*)out);
}

extern "C" void kernel_launch(void* const* d_in, const int* in_sizes, int n_in,
                              void* d_out, int out_size, void* d_ws, size_t ws_size,
                              hipStream_t stream) {
    const void* x     = d_in[0];
    const int*  ei    = (const int*)d_in[1];
    const void* ea    = d_in[2];
    const void* pre_w = d_in[3];
    const void* pre_b = d_in[4];
    const void* W[3]  = {d_in[5], d_in[7], d_in[9]};
    const void* B[3]  = {d_in[6], d_in[8], d_in[10]};
    const int* src = ei;
    const int* tgt = ei + NE;

    // ws layout: EDGE f4[NE] | S f32[NN*192] | H bf16[NN*64] | CNT[NN] (16B-aligned)
    //            | OFF[NN+4] | FILL | INV | FLAG
    float4*         EDGE = (float4*)d_ws;                       // 12.8 MB
    float*          S    = (float*)(EDGE + NE);                 // 38.4 MB
    unsigned short* H    = (unsigned short*)(S + (size_t)NN * 192);  // 6.4 MB
    int*            CNT  = (int*)(H + (size_t)NN * C);          // 16B-aligned
    int*            OFF  = CNT + NN;
    int*            FILL = OFF + NN + 4;
    float*          INV  = (float*)(FILL + NN);
    int*            FLAG = (int*)(INV + NN);

    detect_kernel<<<1, 64, 0, stream>>>((const unsigned*)x, FLAG);
    hipMemsetAsync(CNT, 0, NN * sizeof(int), stream);
    hipMemsetAsync(FILL, 0, NN * sizeof(int), stream);
    count_kernel<<<(NE + 255) / 256, 256, 0, stream>>>(tgt, CNT);
    scan_kernel<<<1, 1024, 0, stream>>>((const int4*)CNT, OFF, INV);
    fill_kernel<<<(NE + 255) / 256, 256, 0, stream>>>(src, tgt, ea, OFF, FLAG, FILL, EDGE);
    pre_kernel<<<(NN + 63) / 64, 256, 0, stream>>>(x, pre_w, pre_b, FLAG, H);

    for (int l = 0; l < 3; ++l) {
        agg_kernel<<<NN / 4, 256, 0, stream>>>(H, EDGE, OFF, INV, S);
        if (l < 2)
            gemm_relu<<<(NN + 63) / 64, 256, 0, stream>>>(S, W[l], B[l], FLAG, H);
        else
            gemm_norm<<<(NN + 63) / 64, 256, 0, stream>>>(S, W[l], B[l], FLAG, d_out);
    }
}